// Round 17
// baseline (2280.280 us; speedup 1.0000x reference)
//
#include <hip/hip_runtime.h>
#include <hip/hip_bf16.h>

typedef unsigned short u16;
typedef __attribute__((ext_vector_type(8))) short bf16x8;
typedef __attribute__((ext_vector_type(8))) u16   u16x8;
typedef __attribute__((ext_vector_type(4))) float f32x4;

#define T_STEPS 256
#define BATCH   128
#define INDIM   512
#define HDIM    1024
#define GDIM    4096
#define KTOT    1536

#define OFF_XBF   ((size_t)0)
#define XBF_BYTES ((size_t)T_STEPS * BATCH * INDIM * 2)   // 33554432
#define OFF_BM    (OFF_XBF + XBF_BYTES)
#define BM_BYTES  ((size_t)2 * GDIM * KTOT * 2)           // 25165824
#define OFF_BIAS  (OFF_BM + BM_BYTES)
#define BIAS_BYTES ((size_t)2 * GDIM * 4)                 // 32768
#define OFF_CNT   (OFF_BIAS + BIAS_BYTES)
#define OFF_ROLL  (OFF_CNT + 8192)
#define ROLL_BYTES ((size_t)(T_STEPS + 1) * 2 * BATCH * HDIM * 2)  // 134742016
#define WS_NEED   (OFF_ROLL + ROLL_BYTES)

__device__ __forceinline__ u16 f2b(float f) {
  __hip_bfloat16 h = __float2bfloat16(f);
  return *reinterpret_cast<u16*>(&h);
}

// async global->LDS, 16B per lane (dest = wave-uniform base + lane*16)
__device__ __forceinline__ void glds16(const void* g, void* l) {
  __builtin_amdgcn_global_load_lds(
      (const __attribute__((address_space(1))) unsigned int*)g,
      (__attribute__((address_space(3))) unsigned int*)l, 16, 0, 0);
}

// ---------------- prepass: cast x to bf16 ----------------
__global__ void k_cast_x(const float* __restrict__ x, u16* __restrict__ xb) {
  size_t i = ((size_t)blockIdx.x * 256 + threadIdx.x) * 8;
  f32x4 a = *reinterpret_cast<const f32x4*>(x + i);
  f32x4 b = *reinterpret_cast<const f32x4*>(x + i + 4);
  u16x8 u;
  u[0] = f2b(a[0]); u[1] = f2b(a[1]); u[2] = f2b(a[2]); u[3] = f2b(a[3]);
  u[4] = f2b(b[0]); u[5] = f2b(b[1]); u[6] = f2b(b[2]); u[7] = f2b(b[3]);
  *reinterpret_cast<u16x8*>(xb + i) = u;
}

// ---------------- prepass: build merged weight matrix ----------------
// Bm[dir][jt][c 0..63][k 0..1535] bf16; col c -> gate row G=(c>>4)*1024+jt*16+(c&15)
__global__ void k_build_b(const float* __restrict__ Whh_f, const float* __restrict__ Wih_f,
                          const float* __restrict__ Whh_r, const float* __restrict__ Wih_r,
                          u16* __restrict__ Bm) {
  int blk = blockIdx.x;              // 0..127 = dir*64 + jt
  int dir = blk >> 6, jt = blk & 63;
  const float* Whh = dir ? Whh_r : Whh_f;
  const float* Wih = dir ? Wih_r : Wih_f;
  u16* dst = Bm + (size_t)blk * 64 * KTOT;
  for (int c = 0; c < 64; c++) {
    int G = (c >> 4) * HDIM + jt * 16 + (c & 15);
    for (int k = threadIdx.x; k < KTOT; k += 256) {
      float v = (k < HDIM) ? Whh[(size_t)G * HDIM + k] : Wih[(size_t)G * INDIM + (k - HDIM)];
      dst[c * KTOT + k] = f2b(v);
    }
  }
}

// ---------------- prepass: init roll slot 0 (SWIZZLED), bias, flags ----------------
__global__ void k_init(const float* __restrict__ h0f, const float* __restrict__ h0r,
                       const float* __restrict__ bihf, const float* __restrict__ bhhf,
                       const float* __restrict__ bihr, const float* __restrict__ bhhr,
                       u16* __restrict__ hroll, float* __restrict__ bias,
                       unsigned* __restrict__ flags) {
  int i = blockIdx.x * 256 + threadIdx.x;
  if (i < 2 * BATCH * HDIM) {
    int dir = i / (BATCH * HDIM);
    int rem = i - dir * BATCH * HDIM;
    int r = rem / HDIM, c = rem - r * HDIM;
    const float* h0 = dir ? h0r : h0f;
    char* hb = (char*)hroll;
    *(u16*)(hb + ((size_t)dir * BATCH + r) * 2048 + ((2 * c) ^ ((r & 7) << 4))) =
        f2b(h0[rem]);
  }
  if (i < 2 * GDIM) {
    int dir = i / GDIM, g = i - dir * GDIM;
    bias[i] = dir ? (bihr[g] + bhhr[g]) : (bihf[g] + bhhf[g]);
  }
  if (i < 512) flags[i] = 0;
}

// ---------------- persistent bidirectional LSTM ----------------
// grid 256 x 512 (1 WG/CU). SINGLE-XCD CHAINS: chain=(dir, batch-quarter q)
// lives entirely on one XCD (32 WGs). WG: M=32 rows x N=128 gate cols x
// K=1536; 8 waves = 4 K-split x 2 N-split. h exchange never leaves the XCD:
// plain write-back stores (dirty in L2, fast vmcnt ack) + same-XCD glds
// stage (64KB) from the pre-swizzled roll; LLC flags for ordering only.
__global__ __launch_bounds__(512, 2) void k_lstm(
    const u16* __restrict__ xb, const u16* __restrict__ Bm,
    u16* __restrict__ hroll,
    const float* __restrict__ bias, unsigned* __restrict__ flags,
    const float* __restrict__ c0f, const float* __restrict__ c0r,
    float* __restrict__ out) {
  __shared__ char ldsc[67584];    // h-stage 32x2048B U partials [4][128][33] f32
  float* ldsP = reinterpret_cast<float*>(ldsc);

  // Invalidate stale L1/L2 lines from a previous graph replay.
  __builtin_amdgcn_fence(__ATOMIC_ACQUIRE, "agent");

  const int wg   = blockIdx.x;
  const int xcd  = wg & 7;                     // round-robin XCD dispatch
  const int dir  = xcd >> 2, q = xcd & 3;      // chain = (dir, q), one XCD
  const int jt32 = wg >> 3;                    // 0..31: owns h-cols [32*jt32,+32)
  const int grp  = dir * 4 + q;
  const int tid  = threadIdx.x;
  const int w = tid >> 6, lane = tid & 63;
  const int kq = w >> 1, nh = w & 1;           // 4-way K x 2-way N
  const int h4 = lane >> 4, kk = h4 * 8;
  const int ar = lane & 15;

  // ---- h/x weight fragments (fragment map into R9's 64-col jt panels) ----
  // col c = nh*64 + ni*16 + ar (0..127) -> gate g = nh*2+(ni>>1),
  // panel jt' = jt32*2 + (ni&1), panel col c' = g*16 + ar.
  bf16x8 bh[8][4], bx[4][4];
#pragma unroll
  for (int ni = 0; ni < 4; ni++) {
    const u16* bp = Bm + (size_t)(dir * 64 + jt32 * 2 + (ni & 1)) * 64 * KTOT
                  + (size_t)((nh * 2 + (ni >> 1)) * 16 + ar) * KTOT;
#pragma unroll
    for (int ks = 0; ks < 8; ks++)
      bh[ks][ni] = *reinterpret_cast<const bf16x8*>(bp + 256 * kq + 32 * ks + kk);
#pragma unroll
    for (int ksx = 0; ksx < 4; ksx++)
      bx[ksx][ni] = *reinterpret_cast<const bf16x8*>(bp + HDIM + 128 * kq + 32 * ksx + kk);
  }

  // ---- gating thread mapping: 1 row x 2 adjacent h-cols ----
  const int rrow = tid >> 4;            // 0..31 local row
  const int jl0  = 2 * (tid & 15);      // 0..30 even
  const int row0 = q * 32 + rrow;       // global batch row
  const int jg0  = jt32 * 32 + jl0;     // global h column (even)
  const float* c0 = dir ? c0r : c0f;
  float2 cc = *reinterpret_cast<const float2*>(c0 + (size_t)row0 * HDIM + jg0);
  float cst0 = cc.x, cst1 = cc.y;
  const float2 b_i = *reinterpret_cast<const float2*>(bias + dir * GDIM + 0 * HDIM + jg0);
  const float2 b_f = *reinterpret_cast<const float2*>(bias + dir * GDIM + 1 * HDIM + jg0);
  const float2 b_g = *reinterpret_cast<const float2*>(bias + dir * GDIM + 2 * HDIM + jg0);
  const float2 b_o = *reinterpret_cast<const float2*>(bias + dir * GDIM + 3 * HDIM + jg0);

  const unsigned* fpA = flags + grp * 32 + (lane & 31);  // 32 producers, 2 lanes each

#pragma unroll 1
  for (int s = 0; s < T_STEPS; s++) {
    const int t = dir ? (T_STEPS - 1 - s) : s;

    // ---- issue x-loads FIRST (older than glds in vmcnt FIFO) ----
    bf16x8 ax[4][2];
    {
      const u16* xsrc = xb + ((size_t)t * BATCH + q * 32) * INDIM;
#pragma unroll
      for (int ksx = 0; ksx < 4; ksx++)
#pragma unroll
        for (int mi = 0; mi < 2; mi++)
          ax[ksx][mi] = *reinterpret_cast<const bf16x8*>(
              xsrc + (size_t)(16 * mi + ar) * INDIM + 128 * kq + 32 * ksx + kk);
    }

    // ---- wait for ALL 32 producers of this chain ----
    if (s > 0) {
      while (true) {
        unsigned f = __hip_atomic_load(fpA, __ATOMIC_RELAXED, __HIP_MEMORY_SCOPE_AGENT);
        if (__all((int)(f >= (unsigned)s))) break;
        __builtin_amdgcn_s_sleep(1);
      }
      __builtin_amdgcn_sched_barrier(0);   // keep glds below the wait
    }

    // ---- stage h tile (64KB: rows [32q,+32), pre-swizzled, linear copy) ----
    {
      const char* hRd = (const char*)hroll
                      + ((size_t)(s * 2 + dir) * BATCH + q * 32) * 2048;
      unsigned off = (unsigned)tid * 16;
#pragma unroll
      for (int i = 0; i < 8; i++)
        glds16(hRd + off + i * 8192, ldsc + off + i * 8192);
    }

    // ---- x MFMAs overlap the glds flight (waitcnt stops at x-loads) ----
    f32x4 acc[2][4];
#pragma unroll
    for (int mi = 0; mi < 2; mi++)
#pragma unroll
      for (int ni = 0; ni < 4; ni++) acc[mi][ni] = f32x4{0.f, 0.f, 0.f, 0.f};
#pragma unroll
    for (int ksx = 0; ksx < 4; ksx++)
#pragma unroll
      for (int mi = 0; mi < 2; mi++)
#pragma unroll
        for (int ni = 0; ni < 4; ni++)
          acc[mi][ni] = __builtin_amdgcn_mfma_f32_16x16x32_bf16(ax[ksx][mi], bx[ksx][ni], acc[mi][ni], 0, 0, 0);

    __syncthreads();   // drains glds; h tile resident in LDS

    // ---- h phase: swizzled conflict-free ds_read_b128 + MFMA ----
#pragma unroll
    for (int ks = 0; ks < 8; ks++) {
      bf16x8 af[2];
#pragma unroll
      for (int mi = 0; mi < 2; mi++) {
        unsigned row = 16 * mi + ar;      // local row 0..31
        unsigned cb = (256 * kq + 32 * ks + kk) * 2;
        af[mi] = *reinterpret_cast<const bf16x8*>(
            ldsc + row * 2048 + (cb ^ ((row & 7) << 4)));
      }
#pragma unroll
      for (int mi = 0; mi < 2; mi++)
#pragma unroll
        for (int ni = 0; ni < 4; ni++)
          acc[mi][ni] = __builtin_amdgcn_mfma_f32_16x16x32_bf16(af[mi], bh[ks][ni], acc[mi][ni], 0, 0, 0);
    }
    __syncthreads();   // h-LDS dead; partials may overwrite

    // ---- write per-wave partials: [kq][col 128][33] f32 ----
    {
      float* pw = ldsP + kq * (128 * 33);
#pragma unroll
      for (int mi = 0; mi < 2; mi++)
#pragma unroll
        for (int ni = 0; ni < 4; ni++) {
          int col = nh * 64 + ni * 16 + ar;
          *reinterpret_cast<f32x4*>(pw + col * 33 + mi * 16 + h4 * 4) = acc[mi][ni];
        }
    }
    __syncthreads();

    // ---- reduce 4 partials + gating (thread: 1 row, 2 h-cols) ----
    float h0v, h1v;
    {
      float gi0 = b_i.x, gi1 = b_i.y, gf0 = b_f.x, gf1 = b_f.y;
      float gg0 = b_g.x, gg1 = b_g.y, go0 = b_o.x, go1 = b_o.y;
#pragma unroll
      for (int k4 = 0; k4 < 4; k4++) {
        const float* p = ldsP + k4 * (128 * 33);
        gi0 += p[(0 * 32 + jl0) * 33 + rrow]; gi1 += p[(0 * 32 + jl0 + 1) * 33 + rrow];
        gf0 += p[(1 * 32 + jl0) * 33 + rrow]; gf1 += p[(1 * 32 + jl0 + 1) * 33 + rrow];
        gg0 += p[(2 * 32 + jl0) * 33 + rrow]; gg1 += p[(2 * 32 + jl0 + 1) * 33 + rrow];
        go0 += p[(3 * 32 + jl0) * 33 + rrow]; go1 += p[(3 * 32 + jl0 + 1) * 33 + rrow];
      }
      float i0 = 1.f / (1.f + __expf(-gi0)), i1 = 1.f / (1.f + __expf(-gi1));
      float f0 = 1.f / (1.f + __expf(-gf0)), f1 = 1.f / (1.f + __expf(-gf1));
      float g0 = tanhf(gg0), g1 = tanhf(gg1);
      float o0 = 1.f / (1.f + __expf(-go0)), o1 = 1.f / (1.f + __expf(-go1));
      cst0 = f0 * cst0 + i0 * g0;
      cst1 = f1 * cst1 + i1 * g1;
      h0v = o0 * tanhf(cst0);
      h1v = o1 * tanhf(cst1);

      // publish h for step s+1: PLAIN write-back store (same-XCD consumers;
      // dirty line stays in this XCD's L2; vmcnt acks at L2)
      unsigned hp = (unsigned)f2b(h0v) | ((unsigned)f2b(h1v) << 16);
      char* hb = (char*)hroll + ((size_t)((s + 1) * 2 + dir) * BATCH) * 2048;
      __hip_atomic_store(
          (unsigned*)(hb + (size_t)row0 * 2048 + ((2 * jg0) ^ ((row0 & 7) << 4))),
          hp, __ATOMIC_RELAXED, __HIP_MEMORY_SCOPE_WORKGROUP);
    }

    // ---- release: ack h stores (L2) -> all waves done -> post LLC flag ----
    asm volatile("s_waitcnt vmcnt(0)" ::: "memory");
    __syncthreads();
    if (tid == 0)
      __hip_atomic_store(flags + grp * 32 + jt32, (unsigned)(s + 1),
                         __ATOMIC_RELAXED, __HIP_MEMORY_SCOPE_AGENT);

    // ---- y stores AFTER the release (off the critical path) ----
    {
      float2 yv; yv.x = h0v; yv.y = h1v;
      *reinterpret_cast<float2*>(out + ((size_t)t * BATCH + row0) * (2 * HDIM)
                                     + (size_t)dir * HDIM + jg0) = yv;
      if (s == T_STEPS - 1) {
        size_t hid = (size_t)T_STEPS * BATCH * 2 * HDIM;
        size_t base2 = hid + (size_t)dir * 2 * BATCH * HDIM;
        *reinterpret_cast<float2*>(out + base2 + (size_t)row0 * HDIM + jg0) = yv;
        float2 cv; cv.x = cst0; cv.y = cst1;
        *reinterpret_cast<float2*>(out + base2 + (size_t)BATCH * HDIM
                                       + (size_t)row0 * HDIM + jg0) = cv;
      }
    }
  }
}

extern "C" void kernel_launch(void* const* d_in, const int* in_sizes, int n_in,
                              void* d_out, int out_size, void* d_ws, size_t ws_size,
                              hipStream_t stream) {
  const float* x     = (const float*)d_in[0];
  const float* h0f   = (const float*)d_in[1];
  const float* c0f   = (const float*)d_in[2];
  const float* h0r   = (const float*)d_in[3];
  const float* c0r   = (const float*)d_in[4];
  const float* Wih_f = (const float*)d_in[5];
  const float* Whh_f = (const float*)d_in[6];
  const float* bih_f = (const float*)d_in[7];
  const float* bhh_f = (const float*)d_in[8];
  const float* Wih_r = (const float*)d_in[9];
  const float* Whh_r = (const float*)d_in[10];
  const float* bih_r = (const float*)d_in[11];
  const float* bhh_r = (const float*)d_in[12];
  float* out = (float*)d_out;
  char* ws = (char*)d_ws;

  if (ws_size < WS_NEED) return;

  u16* xbf        = (u16*)(ws + OFF_XBF);
  u16* Bm         = (u16*)(ws + OFF_BM);
  float* bias     = (float*)(ws + OFF_BIAS);
  unsigned* flags = (unsigned*)(ws + OFF_CNT);
  u16* hroll      = (u16*)(ws + OFF_ROLL);

  k_cast_x<<<8192, 256, 0, stream>>>(x, xbf);
  k_build_b<<<128, 256, 0, stream>>>(Whh_f, Wih_f, Whh_r, Wih_r, Bm);
  k_init<<<1024, 256, 0, stream>>>(h0f, h0r, bih_f, bhh_f, bih_r, bhh_r,
                                   hroll, bias, flags);
  k_lstm<<<256, 512, 0, stream>>>(xbf, Bm, hroll, bias, flags, c0f, c0r, out);
}

// Round 18
// 2037.638 us; speedup vs baseline: 1.1191x; 1.1191x over previous
//
#include <hip/hip_runtime.h>
#include <hip/hip_bf16.h>

typedef unsigned short u16;
typedef __attribute__((ext_vector_type(8))) short bf16x8;
typedef __attribute__((ext_vector_type(8))) u16   u16x8;
typedef __attribute__((ext_vector_type(4))) float f32x4;

#define T_STEPS 256
#define BATCH   128
#define INDIM   512
#define HDIM    1024
#define GDIM    4096
#define KTOT    1536

#define OFF_XBF   ((size_t)0)
#define XBF_BYTES ((size_t)T_STEPS * BATCH * INDIM * 2)   // 33554432
#define OFF_BM    (OFF_XBF + XBF_BYTES)
#define BM_BYTES  ((size_t)2 * GDIM * KTOT * 2)           // 25165824
#define OFF_BIAS  (OFF_BM + BM_BYTES)
#define BIAS_BYTES ((size_t)2 * GDIM * 4)                 // 32768
#define OFF_CNT   (OFF_BIAS + BIAS_BYTES)
#define OFF_ROLL  (OFF_CNT + 8192)
#define ROLL_BYTES ((size_t)(T_STEPS + 1) * 2 * BATCH * HDIM * 2)  // 134742016
#define WS_NEED   (OFF_ROLL + ROLL_BYTES)

__device__ __forceinline__ u16 f2b(float f) {
  __hip_bfloat16 h = __float2bfloat16(f);
  return *reinterpret_cast<u16*>(&h);
}

// async global->LDS, 16B per lane (dest = wave-uniform base + lane*16)
__device__ __forceinline__ void glds16(const void* g, void* l) {
  __builtin_amdgcn_global_load_lds(
      (const __attribute__((address_space(1))) unsigned int*)g,
      (__attribute__((address_space(3))) unsigned int*)l, 16, 0, 0);
}

// ---------------- prepass: cast x to bf16 ----------------
__global__ void k_cast_x(const float* __restrict__ x, u16* __restrict__ xb) {
  size_t i = ((size_t)blockIdx.x * 256 + threadIdx.x) * 8;
  f32x4 a = *reinterpret_cast<const f32x4*>(x + i);
  f32x4 b = *reinterpret_cast<const f32x4*>(x + i + 4);
  u16x8 u;
  u[0] = f2b(a[0]); u[1] = f2b(a[1]); u[2] = f2b(a[2]); u[3] = f2b(a[3]);
  u[4] = f2b(b[0]); u[5] = f2b(b[1]); u[6] = f2b(b[2]); u[7] = f2b(b[3]);
  *reinterpret_cast<u16x8*>(xb + i) = u;
}

// ---------------- prepass: build merged weight matrix ----------------
// Bm[dir][jt][c 0..63][k 0..1535] bf16; col c -> gate row G=(c>>4)*1024+jt*16+(c&15)
__global__ void k_build_b(const float* __restrict__ Whh_f, const float* __restrict__ Wih_f,
                          const float* __restrict__ Whh_r, const float* __restrict__ Wih_r,
                          u16* __restrict__ Bm) {
  int blk = blockIdx.x;              // 0..127 = dir*64 + jt
  int dir = blk >> 6, jt = blk & 63;
  const float* Whh = dir ? Whh_r : Whh_f;
  const float* Wih = dir ? Wih_r : Wih_f;
  u16* dst = Bm + (size_t)blk * 64 * KTOT;
  for (int c = 0; c < 64; c++) {
    int G = (c >> 4) * HDIM + jt * 16 + (c & 15);
    for (int k = threadIdx.x; k < KTOT; k += 256) {
      float v = (k < HDIM) ? Whh[(size_t)G * HDIM + k] : Wih[(size_t)G * INDIM + (k - HDIM)];
      dst[c * KTOT + k] = f2b(v);
    }
  }
}

// ---------------- prepass: init roll slot 0 (SWIZZLED), bias, flags ----------------
__global__ void k_init(const float* __restrict__ h0f, const float* __restrict__ h0r,
                       const float* __restrict__ bihf, const float* __restrict__ bhhf,
                       const float* __restrict__ bihr, const float* __restrict__ bhhr,
                       u16* __restrict__ hroll, float* __restrict__ bias,
                       unsigned* __restrict__ flags) {
  int i = blockIdx.x * 256 + threadIdx.x;
  if (i < 2 * BATCH * HDIM) {
    int dir = i / (BATCH * HDIM);
    int rem = i - dir * BATCH * HDIM;
    int r = rem / HDIM, c = rem - r * HDIM;
    const float* h0 = dir ? h0r : h0f;
    char* hb = (char*)hroll;
    *(u16*)(hb + ((size_t)dir * BATCH + r) * 2048 + ((2 * c) ^ ((r & 7) << 4))) =
        f2b(h0[rem]);
  }
  if (i < 2 * GDIM) {
    int dir = i / GDIM, g = i - dir * GDIM;
    bias[i] = dir ? (bihr[g] + bhhr[g]) : (bihf[g] + bhhf[g]);
  }
  if (i < 512) flags[i] = 0;
}

// ---------------- persistent bidirectional LSTM ----------------
// grid 256 WGs x 512 thr (1/CU). WG=(dir,mt,jt): M=64 x N=64 x K=1536, 8-wave
// K-split, Bh in regs. h tile staged via global_load_lds from a PRE-SWIZZLED
// roll buffer (byte ^= (row&7)<<4 within each 2048B row), fragments via
// conflict-free swizzled ds_read_b128. x-MFMAs overlap the stage flight.
__global__ __launch_bounds__(512, 2) void k_lstm(
    const u16* __restrict__ xb, const u16* __restrict__ Bm,
    u16* __restrict__ hroll,
    const float* __restrict__ bias, unsigned* __restrict__ flags,
    const float* __restrict__ c0f, const float* __restrict__ c0r,
    float* __restrict__ out) {
  __shared__ float ldsf[8 * 64 * 68];   // 139264B: h-stage [0,131072) U partials
  char* ldsc = reinterpret_cast<char*>(ldsf);

  // Invalidate stale L1/L2 lines from a previous graph replay.
  __builtin_amdgcn_fence(__ATOMIC_ACQUIRE, "agent");

  const int wg   = blockIdx.x;
  const int xcd  = wg & 7, local = wg >> 3;    // round-robin XCD dispatch
  const int grp  = xcd >> 1;                   // 0..3 = (dir,mt) chain
  const int dir  = grp >> 1, mt = grp & 1;
  const int jt   = ((xcd & 1) << 5) | local;   // 0..63
  const int tid = threadIdx.x;
  const int w = tid >> 6, lane = tid & 63;
  const int kk = (lane >> 4) * 8;
  const int ar = lane & 15;

  // ---- persistent h-part weight fragments in registers ----
  const u16* bsrc = Bm + (size_t)(dir * 64 + jt) * 64 * KTOT;
  bf16x8 bh[4][4];
#pragma unroll
  for (int ks = 0; ks < 4; ks++)
#pragma unroll
    for (int ni = 0; ni < 4; ni++)
      bh[ks][ni] = *reinterpret_cast<const bf16x8*>(
          bsrc + (size_t)(ni * 16 + ar) * KTOT + 128 * w + 32 * ks + kk);

  // ---- gating thread mapping: 1 row x 2 adjacent cols per thread ----
  const int rrow = tid >> 3;            // 0..63 local row
  const int cp   = tid & 7;             // col pair 0..7
  const int jl0  = 2 * cp;
  const int row0 = mt * 64 + rrow;      // global batch row
  const int jg0  = jt * 16 + jl0;       // global h column (even)
  const float* c0 = dir ? c0r : c0f;
  float2 cc = *reinterpret_cast<const float2*>(c0 + (size_t)row0 * HDIM + jg0);
  float cst0 = cc.x, cst1 = cc.y;
  const float2 b_i = *reinterpret_cast<const float2*>(bias + dir * GDIM + 0 * HDIM + jg0);
  const float2 b_f = *reinterpret_cast<const float2*>(bias + dir * GDIM + 1 * HDIM + jg0);
  const float2 b_g = *reinterpret_cast<const float2*>(bias + dir * GDIM + 2 * HDIM + jg0);
  const float2 b_o = *reinterpret_cast<const float2*>(bias + dir * GDIM + 3 * HDIM + jg0);

  const unsigned* fpA = flags + grp * 64 + lane;  // all 64 producers, one/lane

#pragma unroll 1
  for (int s = 0; s < T_STEPS; s++) {
    const int t = dir ? (T_STEPS - 1 - s) : s;

    // ---- issue x-loads FIRST (older than glds in vmcnt FIFO) ----
    bf16x8 axm[2][4], bxn[2][4];
    {
      const u16* xsrc = xb + ((size_t)t * BATCH + mt * 64) * INDIM;
#pragma unroll
      for (int ks = 0; ks < 2; ks++) {
#pragma unroll
        for (int mi = 0; mi < 4; mi++)
          axm[ks][mi] = *reinterpret_cast<const bf16x8*>(
              xsrc + (size_t)(16 * mi + ar) * INDIM + 64 * w + 32 * ks + kk);
#pragma unroll
        for (int ni = 0; ni < 4; ni++)
          bxn[ks][ni] = *reinterpret_cast<const bf16x8*>(
              bsrc + (size_t)(ni * 16 + ar) * KTOT + HDIM + 64 * w + 32 * ks + kk);
      }
    }

    // ---- wait for ALL 64 producers of this chain (cooperative staging) ----
    if (s > 0) {
      while (true) {
        unsigned f = __hip_atomic_load(fpA, __ATOMIC_RELAXED, __HIP_MEMORY_SCOPE_AGENT);
        if (__all((int)(f >= (unsigned)s))) break;
        __builtin_amdgcn_s_sleep(1);
      }
      __builtin_amdgcn_sched_barrier(0);   // keep glds below the wait
    }

    // ---- stage h tile (128KB, pre-swizzled bytes, linear copy) ----
    {
      const char* hRd = (const char*)(hroll + ((size_t)s * 2 + dir) * BATCH * HDIM
                                            + (size_t)mt * 64 * HDIM);
      unsigned off = (unsigned)w * 1024 + (unsigned)(lane * 16);
#pragma unroll
      for (int i = 0; i < 16; i++)
        glds16(hRd + off + i * 8192, ldsc + off + i * 8192);
    }

    // ---- x MFMAs overlap the glds flight (waitcnt stops at x-loads) ----
    f32x4 acc[4][4];
#pragma unroll
    for (int mi = 0; mi < 4; mi++)
#pragma unroll
      for (int ni = 0; ni < 4; ni++) acc[mi][ni] = f32x4{0.f, 0.f, 0.f, 0.f};
#pragma unroll
    for (int ks = 0; ks < 2; ks++)
#pragma unroll
      for (int mi = 0; mi < 4; mi++)
#pragma unroll
        for (int ni = 0; ni < 4; ni++)
          acc[mi][ni] = __builtin_amdgcn_mfma_f32_16x16x32_bf16(axm[ks][mi], bxn[ks][ni], acc[mi][ni], 0, 0, 0);

    __syncthreads();   // drains glds; h tile resident in LDS

    // ---- h phase: swizzled conflict-free ds_read_b128 + MFMA ----
#pragma unroll
    for (int ks = 0; ks < 4; ks++)
#pragma unroll
      for (int mi = 0; mi < 4; mi++) {
        unsigned row = 16 * mi + ar;
        unsigned cb = (128 * w + 32 * ks + kk) * 2;
        bf16x8 af = *reinterpret_cast<const bf16x8*>(
            ldsc + row * 2048 + (cb ^ ((row & 7) << 4)));
#pragma unroll
        for (int ni = 0; ni < 4; ni++)
          acc[mi][ni] = __builtin_amdgcn_mfma_f32_16x16x32_bf16(af, bh[ks][ni], acc[mi][ni], 0, 0, 0);
      }
    __syncthreads();   // h-LDS dead; partials may overwrite

    // ---- write per-wave partials: [w][c 64][68 r] f32, col-major ----
    {
      float* pw = ldsf + w * (64 * 68);
#pragma unroll
      for (int mi = 0; mi < 4; mi++)
#pragma unroll
        for (int ni = 0; ni < 4; ni++)
          *reinterpret_cast<f32x4*>(pw + (ni * 16 + ar) * 68 + mi * 16 + (lane >> 4) * 4) = acc[mi][ni];
    }
    __syncthreads();

    // ---- reduce 8 partials + gating (thread: 1 row, 2 cols) ----
    float h0v, h1v;
    {
      float gi0 = b_i.x, gi1 = b_i.y, gf0 = b_f.x, gf1 = b_f.y;
      float gg0 = b_g.x, gg1 = b_g.y, go0 = b_o.x, go1 = b_o.y;
#pragma unroll
      for (int ww = 0; ww < 8; ww++) {
        const float* p = ldsf + ww * (64 * 68);
        gi0 += p[(0 * 16 + jl0) * 68 + rrow]; gi1 += p[(0 * 16 + jl0 + 1) * 68 + rrow];
        gf0 += p[(1 * 16 + jl0) * 68 + rrow]; gf1 += p[(1 * 16 + jl0 + 1) * 68 + rrow];
        gg0 += p[(2 * 16 + jl0) * 68 + rrow]; gg1 += p[(2 * 16 + jl0 + 1) * 68 + rrow];
        go0 += p[(3 * 16 + jl0) * 68 + rrow]; go1 += p[(3 * 16 + jl0 + 1) * 68 + rrow];
      }
      float i0 = 1.f / (1.f + __expf(-gi0)), i1 = 1.f / (1.f + __expf(-gi1));
      float f0 = 1.f / (1.f + __expf(-gf0)), f1 = 1.f / (1.f + __expf(-gf1));
      float g0 = tanhf(gg0), g1 = tanhf(gg1);
      float o0 = 1.f / (1.f + __expf(-go0)), o1 = 1.f / (1.f + __expf(-go1));
      cst0 = f0 * cst0 + i0 * g0;
      cst1 = f1 * cst1 + i1 * g1;
      h0v = o0 * tanhf(cst0);
      h1v = o1 * tanhf(cst1);

      // publish h for step s+1 (SWIZZLED layout, write-through to LLC)
      unsigned hp = (unsigned)f2b(h0v) | ((unsigned)f2b(h1v) << 16);
      char* hb = (char*)(hroll + ((size_t)(s + 1) * 2 + dir) * BATCH * HDIM);
      __hip_atomic_store(
          (unsigned*)(hb + (size_t)row0 * 2048 + ((2 * jg0) ^ ((row0 & 7) << 4))),
          hp, __ATOMIC_RELAXED, __HIP_MEMORY_SCOPE_AGENT);
    }

    // ---- release: ack h stores -> all waves done -> post flag ----
    asm volatile("s_waitcnt vmcnt(0)" ::: "memory");
    __syncthreads();
    if (tid == 0)
      __hip_atomic_store(flags + grp * 64 + jt, (unsigned)(s + 1),
                         __ATOMIC_RELAXED, __HIP_MEMORY_SCOPE_AGENT);

    // ---- y stores AFTER the release (off the critical path) ----
    {
      float2 yv; yv.x = h0v; yv.y = h1v;
      *reinterpret_cast<float2*>(out + ((size_t)t * BATCH + row0) * (2 * HDIM)
                                     + (size_t)dir * HDIM + jg0) = yv;
      if (s == T_STEPS - 1) {
        size_t hid = (size_t)T_STEPS * BATCH * 2 * HDIM;
        size_t base2 = hid + (size_t)dir * 2 * BATCH * HDIM;
        *reinterpret_cast<float2*>(out + base2 + (size_t)row0 * HDIM + jg0) = yv;
        float2 cv; cv.x = cst0; cv.y = cst1;
        *reinterpret_cast<float2*>(out + base2 + (size_t)BATCH * HDIM
                                       + (size_t)row0 * HDIM + jg0) = cv;
      }
    }
  }
}

extern "C" void kernel_launch(void* const* d_in, const int* in_sizes, int n_in,
                              void* d_out, int out_size, void* d_ws, size_t ws_size,
                              hipStream_t stream) {
  const float* x     = (const float*)d_in[0];
  const float* h0f   = (const float*)d_in[1];
  const float* c0f   = (const float*)d_in[2];
  const float* h0r   = (const float*)d_in[3];
  const float* c0r   = (const float*)d_in[4];
  const float* Wih_f = (const float*)d_in[5];
  const float* Whh_f = (const float*)d_in[6];
  const float* bih_f = (const float*)d_in[7];
  const float* bhh_f = (const float*)d_in[8];
  const float* Wih_r = (const float*)d_in[9];
  const float* Whh_r = (const float*)d_in[10];
  const float* bih_r = (const float*)d_in[11];
  const float* bhh_r = (const float*)d_in[12];
  float* out = (float*)d_out;
  char* ws = (char*)d_ws;

  if (ws_size < WS_NEED) return;

  u16* xbf        = (u16*)(ws + OFF_XBF);
  u16* Bm         = (u16*)(ws + OFF_BM);
  float* bias     = (float*)(ws + OFF_BIAS);
  unsigned* flags = (unsigned*)(ws + OFF_CNT);
  u16* hroll      = (u16*)(ws + OFF_ROLL);

  k_cast_x<<<8192, 256, 0, stream>>>(x, xbf);
  k_build_b<<<128, 256, 0, stream>>>(Whh_f, Wih_f, Whh_r, Wih_r, Bm);
  k_init<<<1024, 256, 0, stream>>>(h0f, h0r, bih_f, bhh_f, bih_r, bhh_r,
                                   hroll, bias, flags);
  k_lstm<<<256, 512, 0, stream>>>(xbf, Bm, hroll, bias, flags, c0f, c0r, out);
}

// Round 19
// 2002.050 us; speedup vs baseline: 1.1390x; 1.0178x over previous
//
#include <hip/hip_runtime.h>
#include <hip/hip_bf16.h>

typedef unsigned short u16;
typedef __attribute__((ext_vector_type(8))) short bf16x8;
typedef __attribute__((ext_vector_type(8))) u16   u16x8;
typedef __attribute__((ext_vector_type(4))) float f32x4;

#define T_STEPS 256
#define BATCH   128
#define INDIM   512
#define HDIM    1024
#define GDIM    4096
#define KTOT    1536

#define OFF_XBF   ((size_t)0)
#define XBF_BYTES ((size_t)T_STEPS * BATCH * INDIM * 2)   // 33554432
#define OFF_BM    (OFF_XBF + XBF_BYTES)
#define BM_BYTES  ((size_t)2 * GDIM * KTOT * 2)           // 25165824
#define OFF_BIAS  (OFF_BM + BM_BYTES)
#define BIAS_BYTES ((size_t)2 * GDIM * 4)                 // 32768
#define OFF_CNT   (OFF_BIAS + BIAS_BYTES)
#define OFF_ROLL  (OFF_CNT + 8192)
#define ROLL_BYTES ((size_t)(T_STEPS + 1) * 2 * BATCH * HDIM * 2)  // 134742016
#define WS_NEED   (OFF_ROLL + ROLL_BYTES)

__device__ __forceinline__ u16 f2b(float f) {
  __hip_bfloat16 h = __float2bfloat16(f);
  return *reinterpret_cast<u16*>(&h);
}

// async global->LDS, 16B per lane (dest = wave-uniform base + lane*16)
__device__ __forceinline__ void glds16(const void* g, void* l) {
  __builtin_amdgcn_global_load_lds(
      (const __attribute__((address_space(1))) unsigned int*)g,
      (__attribute__((address_space(3))) unsigned int*)l, 16, 0, 0);
}

// ---------------- prepass: cast x to bf16 ----------------
__global__ void k_cast_x(const float* __restrict__ x, u16* __restrict__ xb) {
  size_t i = ((size_t)blockIdx.x * 256 + threadIdx.x) * 8;
  f32x4 a = *reinterpret_cast<const f32x4*>(x + i);
  f32x4 b = *reinterpret_cast<const f32x4*>(x + i + 4);
  u16x8 u;
  u[0] = f2b(a[0]); u[1] = f2b(a[1]); u[2] = f2b(a[2]); u[3] = f2b(a[3]);
  u[4] = f2b(b[0]); u[5] = f2b(b[1]); u[6] = f2b(b[2]); u[7] = f2b(b[3]);
  *reinterpret_cast<u16x8*>(xb + i) = u;
}

// ---------------- prepass: build merged weight matrix ----------------
// Bm[dir][jt][c 0..63][k 0..1535] bf16; col c -> gate row G=(c>>4)*1024+jt*16+(c&15)
__global__ void k_build_b(const float* __restrict__ Whh_f, const float* __restrict__ Wih_f,
                          const float* __restrict__ Whh_r, const float* __restrict__ Wih_r,
                          u16* __restrict__ Bm) {
  int blk = blockIdx.x;              // 0..127 = dir*64 + jt
  int dir = blk >> 6, jt = blk & 63;
  const float* Whh = dir ? Whh_r : Whh_f;
  const float* Wih = dir ? Wih_r : Wih_f;
  u16* dst = Bm + (size_t)blk * 64 * KTOT;
  for (int c = 0; c < 64; c++) {
    int G = (c >> 4) * HDIM + jt * 16 + (c & 15);
    for (int k = threadIdx.x; k < KTOT; k += 256) {
      float v = (k < HDIM) ? Whh[(size_t)G * HDIM + k] : Wih[(size_t)G * INDIM + (k - HDIM)];
      dst[c * KTOT + k] = f2b(v);
    }
  }
}

// ---------------- prepass: init roll slot 0 (SWIZZLED), bias, flags ----------------
__global__ void k_init(const float* __restrict__ h0f, const float* __restrict__ h0r,
                       const float* __restrict__ bihf, const float* __restrict__ bhhf,
                       const float* __restrict__ bihr, const float* __restrict__ bhhr,
                       u16* __restrict__ hroll, float* __restrict__ bias,
                       unsigned* __restrict__ flags) {
  int i = blockIdx.x * 256 + threadIdx.x;
  if (i < 2 * BATCH * HDIM) {
    int dir = i / (BATCH * HDIM);
    int rem = i - dir * BATCH * HDIM;
    int r = rem / HDIM, c = rem - r * HDIM;
    const float* h0 = dir ? h0r : h0f;
    char* hb = (char*)hroll;
    *(u16*)(hb + ((size_t)dir * BATCH + r) * 2048 + ((2 * c) ^ ((r & 7) << 4))) =
        f2b(h0[rem]);
  }
  if (i < 2 * GDIM) {
    int dir = i / GDIM, g = i - dir * GDIM;
    bias[i] = dir ? (bihr[g] + bhhr[g]) : (bihf[g] + bhhf[g]);
  }
  if (i < 512) flags[i] = 0;
}

// ---------------- persistent bidirectional LSTM ----------------
// R16 chassis, WAVE-PRIVATE slices: wave w owns LDS slice [16KB*w, +16KB).
// Stage: wave copies its OWN h K-chunk window (256B/row x 64 rows, swizzle
// window-closed) via glds; per-wave vmcnt(0) replaces the stage barrier.
// h-MFMAs read own slice; partials overwrite own slice (64x64 f32 = 16KB,
// XOR r^((c&7)<<2)). Only 2 barriers/step: pre-reduce + pre-flag.
__global__ __launch_bounds__(512, 2) void k_lstm(
    const u16* __restrict__ xb, const u16* __restrict__ Bm,
    u16* __restrict__ hroll,
    const float* __restrict__ bias, unsigned* __restrict__ flags,
    const float* __restrict__ c0f, const float* __restrict__ c0r,
    float* __restrict__ out) {
  __shared__ char ldsc[131072];   // 8 wave slices x 16KB (h-stage then partials)
  float* ldsF = reinterpret_cast<float*>(ldsc);

  // Invalidate stale L1/L2 lines from a previous graph replay.
  __builtin_amdgcn_fence(__ATOMIC_ACQUIRE, "agent");

  const int wg   = blockIdx.x;
  const int xcd  = wg & 7, local = wg >> 3;    // round-robin XCD dispatch
  const int grp  = xcd >> 1;                   // 0..3 = (dir,mt) chain
  const int dir  = grp >> 1, mt = grp & 1;
  const int jt   = ((xcd & 1) << 5) | local;   // 0..63
  const int tid = threadIdx.x;
  const int w = tid >> 6, lane = tid & 63;
  const int h4 = lane >> 4, kk = h4 * 8;
  const int ar = lane & 15;

  // ---- persistent h-part weight fragments in registers ----
  const u16* bsrc = Bm + (size_t)(dir * 64 + jt) * 64 * KTOT;
  bf16x8 bh[4][4];
#pragma unroll
  for (int ks = 0; ks < 4; ks++)
#pragma unroll
    for (int ni = 0; ni < 4; ni++)
      bh[ks][ni] = *reinterpret_cast<const bf16x8*>(
          bsrc + (size_t)(ni * 16 + ar) * KTOT + 128 * w + 32 * ks + kk);

  // ---- gating thread mapping: 1 row x 2 adjacent cols per thread ----
  const int rrow = tid >> 3;            // 0..63 local row
  const int cp   = tid & 7;             // col pair 0..7
  const int jl0  = 2 * cp;
  const int row0 = mt * 64 + rrow;      // global batch row
  const int jg0  = jt * 16 + jl0;       // global h column (even)
  const float* c0 = dir ? c0r : c0f;
  float2 cc = *reinterpret_cast<const float2*>(c0 + (size_t)row0 * HDIM + jg0);
  float cst0 = cc.x, cst1 = cc.y;
  const float2 b_i = *reinterpret_cast<const float2*>(bias + dir * GDIM + 0 * HDIM + jg0);
  const float2 b_f = *reinterpret_cast<const float2*>(bias + dir * GDIM + 1 * HDIM + jg0);
  const float2 b_g = *reinterpret_cast<const float2*>(bias + dir * GDIM + 2 * HDIM + jg0);
  const float2 b_o = *reinterpret_cast<const float2*>(bias + dir * GDIM + 3 * HDIM + jg0);

  // reduce read swizzle constants (partials layout r ^ ((c&7)<<2))
  const int xr0 = rrow ^ ((jl0 & 7) << 2);
  const int xr1 = rrow ^ (((jl0 + 1) & 7) << 2);

  const unsigned* fpA = flags + grp * 64 + lane;  // all 64 producers, one/lane

#pragma unroll 1
  for (int s = 0; s < T_STEPS; s++) {
    const int t = dir ? (T_STEPS - 1 - s) : s;

    // ---- issue x-loads FIRST (older than glds in vmcnt FIFO) ----
    bf16x8 axm[2][4], bxn[2][4];
    {
      const u16* xsrc = xb + ((size_t)t * BATCH + mt * 64) * INDIM;
#pragma unroll
      for (int ks = 0; ks < 2; ks++) {
#pragma unroll
        for (int mi = 0; mi < 4; mi++)
          axm[ks][mi] = *reinterpret_cast<const bf16x8*>(
              xsrc + (size_t)(16 * mi + ar) * INDIM + 64 * w + 32 * ks + kk);
#pragma unroll
        for (int ni = 0; ni < 4; ni++)
          bxn[ks][ni] = *reinterpret_cast<const bf16x8*>(
              bsrc + (size_t)(ni * 16 + ar) * KTOT + HDIM + 64 * w + 32 * ks + kk);
      }
    }

    // ---- wait for ALL 64 producers of this chain ----
    if (s > 0) {
      while (true) {
        unsigned f = __hip_atomic_load(fpA, __ATOMIC_RELAXED, __HIP_MEMORY_SCOPE_AGENT);
        if (__all((int)(f >= (unsigned)s))) break;
        __builtin_amdgcn_s_sleep(1);
      }
      __builtin_amdgcn_sched_barrier(0);   // keep glds below the wait
    }

    // ---- stage OWN 16KB h-slice: rows 0..63, col-byte window [256w,+256) ----
    // (window is closed under the (r&7)<<4 XOR -> verbatim copy keeps swizzle)
    {
      const char* hRd = (const char*)(hroll + ((size_t)s * 2 + dir) * BATCH * HDIM
                                            + (size_t)mt * 64 * HDIM);
#pragma unroll
      for (int i = 0; i < 16; i++) {
        int r = i * 4 + (lane >> 4);
        glds16(hRd + (size_t)r * 2048 + 256 * w + (lane & 15) * 16,
               ldsc + w * 16384 + i * 1024 + lane * 16);
      }
    }

    // ---- x MFMAs overlap the glds flight ----
    f32x4 acc[4][4];
#pragma unroll
    for (int mi = 0; mi < 4; mi++)
#pragma unroll
      for (int ni = 0; ni < 4; ni++) acc[mi][ni] = f32x4{0.f, 0.f, 0.f, 0.f};
#pragma unroll
    for (int ks = 0; ks < 2; ks++)
#pragma unroll
      for (int mi = 0; mi < 4; mi++)
#pragma unroll
        for (int ni = 0; ni < 4; ni++)
          acc[mi][ni] = __builtin_amdgcn_mfma_f32_16x16x32_bf16(axm[ks][mi], bxn[ks][ni], acc[mi][ni], 0, 0, 0);

    // ---- per-wave drain of own glds (NO barrier) ----
    asm volatile("s_waitcnt vmcnt(0)" ::: "memory");
    __builtin_amdgcn_sched_barrier(0);

    // ---- h phase: own-slice swizzled ds_read_b128 + MFMA ----
#pragma unroll
    for (int ks = 0; ks < 4; ks++)
#pragma unroll
      for (int mi = 0; mi < 4; mi++) {
        unsigned row = 16 * mi + ar;
        unsigned cbl = (32 * ks + kk) * 2;           // col-byte within window
        bf16x8 af = *reinterpret_cast<const bf16x8*>(
            ldsc + w * 16384 + row * 256 + (cbl ^ ((row & 7) << 4)));
#pragma unroll
        for (int ni = 0; ni < 4; ni++)
          acc[mi][ni] = __builtin_amdgcn_mfma_f32_16x16x32_bf16(af, bh[ks][ni], acc[mi][ni], 0, 0, 0);
      }

    // ---- write partials into OWN slice (overwrite own h data; no barrier) ----
    {
      float* pw = ldsF + w * 4096;
#pragma unroll
      for (int mi = 0; mi < 4; mi++)
#pragma unroll
        for (int ni = 0; ni < 4; ni++) {
          int c = ni * 16 + ar;
          int r = mi * 16 + h4 * 4;
          *reinterpret_cast<f32x4*>(pw + c * 64 + (r ^ ((c & 7) << 2))) = acc[mi][ni];
        }
    }
    __syncthreads();   // barrier 1: all partials visible

    // ---- reduce 8 partials + gating (thread: 1 row, 2 cols) ----
    float h0v, h1v;
    {
      float gi0 = b_i.x, gi1 = b_i.y, gf0 = b_f.x, gf1 = b_f.y;
      float gg0 = b_g.x, gg1 = b_g.y, go0 = b_o.x, go1 = b_o.y;
#pragma unroll
      for (int ww = 0; ww < 8; ww++) {
        const float* p = ldsF + ww * 4096;
        gi0 += p[(0 * 16 + jl0) * 64 + xr0]; gi1 += p[(0 * 16 + jl0 + 1) * 64 + xr1];
        gf0 += p[(1 * 16 + jl0) * 64 + xr0]; gf1 += p[(1 * 16 + jl0 + 1) * 64 + xr1];
        gg0 += p[(2 * 16 + jl0) * 64 + xr0]; gg1 += p[(2 * 16 + jl0 + 1) * 64 + xr1];
        go0 += p[(3 * 16 + jl0) * 64 + xr0]; go1 += p[(3 * 16 + jl0 + 1) * 64 + xr1];
      }
      float i0 = 1.f / (1.f + __expf(-gi0)), i1 = 1.f / (1.f + __expf(-gi1));
      float f0 = 1.f / (1.f + __expf(-gf0)), f1 = 1.f / (1.f + __expf(-gf1));
      float g0 = tanhf(gg0), g1 = tanhf(gg1);
      float o0 = 1.f / (1.f + __expf(-go0)), o1 = 1.f / (1.f + __expf(-go1));
      cst0 = f0 * cst0 + i0 * g0;
      cst1 = f1 * cst1 + i1 * g1;
      h0v = o0 * tanhf(cst0);
      h1v = o1 * tanhf(cst1);

      // publish h for step s+1 (SWIZZLED layout, write-through to LLC)
      unsigned hp = (unsigned)f2b(h0v) | ((unsigned)f2b(h1v) << 16);
      char* hb = (char*)(hroll + ((size_t)(s + 1) * 2 + dir) * BATCH * HDIM);
      __hip_atomic_store(
          (unsigned*)(hb + (size_t)row0 * 2048 + ((2 * jg0) ^ ((row0 & 7) << 4))),
          hp, __ATOMIC_RELAXED, __HIP_MEMORY_SCOPE_AGENT);
    }

    // ---- release: ack h stores -> all waves done -> post flag ----
    asm volatile("s_waitcnt vmcnt(0)" ::: "memory");
    __syncthreads();   // barrier 2: publishes + reduce-reads complete
    if (tid == 0)
      __hip_atomic_store(flags + grp * 64 + jt, (unsigned)(s + 1),
                         __ATOMIC_RELAXED, __HIP_MEMORY_SCOPE_AGENT);

    // ---- y stores AFTER the release (off the critical path) ----
    {
      float2 yv; yv.x = h0v; yv.y = h1v;
      *reinterpret_cast<float2*>(out + ((size_t)t * BATCH + row0) * (2 * HDIM)
                                     + (size_t)dir * HDIM + jg0) = yv;
      if (s == T_STEPS - 1) {
        size_t hid = (size_t)T_STEPS * BATCH * 2 * HDIM;
        size_t base2 = hid + (size_t)dir * 2 * BATCH * HDIM;
        *reinterpret_cast<float2*>(out + base2 + (size_t)row0 * HDIM + jg0) = yv;
        float2 cv; cv.x = cst0; cv.y = cst1;
        *reinterpret_cast<float2*>(out + base2 + (size_t)BATCH * HDIM
                                       + (size_t)row0 * HDIM + jg0) = cv;
      }
    }
  }
}

extern "C" void kernel_launch(void* const* d_in, const int* in_sizes, int n_in,
                              void* d_out, int out_size, void* d_ws, size_t ws_size,
                              hipStream_t stream) {
  const float* x     = (const float*)d_in[0];
  const float* h0f   = (const float*)d_in[1];
  const float* c0f   = (const float*)d_in[2];
  const float* h0r   = (const float*)d_in[3];
  const float* c0r   = (const float*)d_in[4];
  const float* Wih_f = (const float*)d_in[5];
  const float* Whh_f = (const float*)d_in[6];
  const float* bih_f = (const float*)d_in[7];
  const float* bhh_f = (const float*)d_in[8];
  const float* Wih_r = (const float*)d_in[9];
  const float* Whh_r = (const float*)d_in[10];
  const float* bih_r = (const float*)d_in[11];
  const float* bhh_r = (const float*)d_in[12];
  float* out = (float*)d_out;
  char* ws = (char*)d_ws;

  if (ws_size < WS_NEED) return;

  u16* xbf        = (u16*)(ws + OFF_XBF);
  u16* Bm         = (u16*)(ws + OFF_BM);
  float* bias     = (float*)(ws + OFF_BIAS);
  unsigned* flags = (unsigned*)(ws + OFF_CNT);
  u16* hroll      = (u16*)(ws + OFF_ROLL);

  k_cast_x<<<8192, 256, 0, stream>>>(x, xbf);
  k_build_b<<<128, 256, 0, stream>>>(Whh_f, Wih_f, Whh_r, Wih_r, Bm);
  k_init<<<1024, 256, 0, stream>>>(h0f, h0r, bih_f, bhh_f, bih_r, bhh_r,
                                   hroll, bias, flags);
  k_lstm<<<256, 512, 0, stream>>>(xbf, Bm, hroll, bias, flags, c0f, c0r, out);
}